// Round 3
// baseline (550.648 us; speedup 1.0000x reference)
//
#include <hip/hip_runtime.h>
#include <hip/hip_bf16.h>

typedef unsigned short u16;
typedef __bf16 bf16x8 __attribute__((ext_vector_type(8)));
typedef float f32x4 __attribute__((ext_vector_type(4)));
typedef unsigned short u16x8 __attribute__((ext_vector_type(8)));

// ---------- helpers ----------
__device__ __forceinline__ void async_copy16(void* lds, const void* g) {
  __builtin_amdgcn_global_load_lds(
      (const __attribute__((address_space(1))) unsigned int*)g,
      (__attribute__((address_space(3))) unsigned int*)lds, 16, 0, 0);
}

__device__ __forceinline__ u16 f2bf(float f) {
  __hip_bfloat16 h = __float2bfloat16(f);
  u16 u;
  __builtin_memcpy(&u, &h, 2);
  return u;
}

// ---------- f32 -> bf16 convert (vectorized) ----------
__global__ void k_f32_to_bf16(const float* __restrict__ in, u16* __restrict__ out, int n4) {
  int i = blockIdx.x * blockDim.x + threadIdx.x;
  if (i >= n4) return;
  float4 v = ((const float4*)in)[i];
  ushort4 o;
  o.x = f2bf(v.x); o.y = f2bf(v.y); o.z = f2bf(v.z); o.w = f2bf(v.w);
  ((ushort4*)out)[i] = o;
}

// ---------- transpose RxC f32 -> CxR bf16 ----------
__global__ void k_transpose_bf16(const float* __restrict__ in, u16* __restrict__ out, int R, int C) {
  __shared__ float tile[32][33];
  int bx = blockIdx.x * 32;
  int by = blockIdx.y * 32;
  int tx = threadIdx.x & 31, ty = threadIdx.x >> 5;
  for (int i = ty; i < 32; i += 8) tile[i][tx] = in[(size_t)(by + i) * C + bx + tx];
  __syncthreads();
  for (int i = ty; i < 32; i += 8) out[(size_t)(bx + i) * R + by + tx] = f2bf(tile[tx][i]);
}

// ---------- GEMM: C(MxN) = A(MxK,bf16) @ Bt(NxK,bf16)^T + bias ----------
template <int OUT_BF16>
__global__ __launch_bounds__(256, 2) void k_gemm_bt(
    const u16* __restrict__ A, const u16* __restrict__ Bt,
    const float* __restrict__ bias, void* __restrict__ Cout,
    int M, int N, int K) {
  __shared__ __align__(16) u16 As[128][32];
  __shared__ __align__(16) u16 Bs[128][32];
  const int t = threadIdx.x;
  const int l = t & 63, w = t >> 6;
  const int lr = l & 15, lk = l >> 4;
  const int wr = w >> 1, wc = w & 1;
  const int m0 = blockIdx.x * 128, n0 = blockIdx.y * 128;

  f32x4 acc[4][4] = {};

  for (int k0 = 0; k0 < K; k0 += 32) {
    __syncthreads();
    for (int c = 0; c < 2; ++c) {
      int idx = c * 256 + t;
      int row = idx >> 2, slot = idx & 3;
      int sw = (slot ^ ((row >> 1) & 3)) << 3;
      async_copy16((char*)&As[0][0] + idx * 16, A + (size_t)(m0 + row) * K + k0 + sw);
      async_copy16((char*)&Bs[0][0] + idx * 16, Bt + (size_t)(n0 + row) * K + k0 + sw);
    }
    __syncthreads();
    bf16x8 af[4], bfr[4];
    for (int m = 0; m < 4; ++m) {
      int row = wr * 64 + m * 16 + lr;
      af[m] = *(const bf16x8*)((const char*)&As[0][0] + row * 64 + ((lk ^ ((row >> 1) & 3)) << 4));
    }
    for (int n = 0; n < 4; ++n) {
      int row = wc * 64 + n * 16 + lr;
      bfr[n] = *(const bf16x8*)((const char*)&Bs[0][0] + row * 64 + ((lk ^ ((row >> 1) & 3)) << 4));
    }
    for (int m = 0; m < 4; ++m)
      for (int n = 0; n < 4; ++n)
        acc[m][n] = __builtin_amdgcn_mfma_f32_16x16x32_bf16(af[m], bfr[n], acc[m][n], 0, 0, 0);
  }

  for (int n = 0; n < 4; ++n) {
    int col = n0 + wc * 64 + n * 16 + lr;
    float bv = bias[col];
    for (int m = 0; m < 4; ++m) {
      int rowb = m0 + wr * 64 + m * 16 + lk * 4;
      for (int r = 0; r < 4; ++r) {
        float v = acc[m][n][r] + bv;
        size_t off = (size_t)(rowb + r) * N + col;
        if constexpr (OUT_BF16) ((u16*)Cout)[off] = f2bf(v);
        else ((float*)Cout)[off] = v;
      }
    }
  }
}

// ---------- flash attention, causal, bf16, paired q-tiles, 8 waves ----------
// grid (8, B*H); block 512 = 8 waves x 16 q-rows per q-tile. Block p handles
// q-tiles p (A) and 15-p (B) jointly -> 34 uniform tile-units. KV dbuf,
// 1 barrier/tile. exp2-folded softmax, defer-max (raw thr=64).
__global__ __launch_bounds__(512, 4) void k_attn(
    const u16* __restrict__ QKV,  // (B*S) x 3072 bf16: [Q|K|V]
    u16* __restrict__ O) {        // (B*S) x 1024 bf16
  const int p = blockIdx.x;   // 0..7
  const int bh = blockIdx.y;  // 0..63
  const int b = bh >> 4, h = bh & 15;
  const int t = threadIdx.x;
  const int l = t & 63, w = t >> 6;  // 8 waves
  const int lr = l & 15, lk = l >> 4;
  constexpr float LG = 0.18033688f;  // 0.125 * log2(e)

  __shared__ __align__(16) u16 Ks[2][64][64];  // key tiles (src-swizzled), dbuf
  __shared__ __align__(16) u16 VT[2][64][64];  // V^T tiles (two-sided swizzle), dbuf
  __shared__ __align__(16) u16 Pl[8][32][72];  // per-wave P: rows 0-15 = A, 16-31 = B

  const int qtA = p, qtB = 15 - p;
  const int ntA = 2 * qtA + 2, ntB = 2 * qtB + 2;  // sum = 34
  const int q0A = qtA * 128 + w * 16, q0B = qtB * 128 + w * 16;
  const size_t rowQA = (size_t)b * 2048 + q0A;
  const size_t rowQB = (size_t)b * 2048 + q0B;

  bf16x8 qfA[2], qfB[2];
#pragma unroll
  for (int c = 0; c < 2; ++c) {
    qfA[c] = *(const bf16x8*)(QKV + (rowQA + lr) * 3072 + h * 64 + c * 32 + lk * 8);
    qfB[c] = *(const bf16x8*)(QKV + (rowQB + lr) * 3072 + h * 64 + c * 32 + lk * 8);
  }

  f32x4 accA[4] = {}, accB[4] = {};
  float miA[4], liA[4], miB[4], liB[4];
#pragma unroll
  for (int r = 0; r < 4; ++r) {
    miA[r] = -__builtin_inff(); liA[r] = 0.f;
    miB[r] = -__builtin_inff(); liB[r] = 0.f;
  }

  const u16* Kb0 = QKV + (size_t)b * 2048 * 3072 + 1024 + h * 64;
  const u16* Vb0 = Kb0 + 1024;
  u16x8 vreg;

  auto stageK = [&](int j, int buf) {  // 512 threads cover 64x64 tile
    int row = t >> 3, slot = t & 7;
    async_copy16((char*)&Ks[buf][0][0] + t * 16,
                 Kb0 + ((size_t)j * 64 + row) * 3072 + ((slot ^ (row & 7)) << 3));
  };
  auto loadV = [&](int j) {
    vreg = *(const u16x8*)(Vb0 + ((size_t)j * 64 + (t >> 3)) * 3072 + ((t & 7) << 3));
  };
  auto writeV = [&](int buf) {
    int r = t >> 3, dh0 = (t & 7) << 3;
#pragma unroll
    for (int jj = 0; jj < 8; ++jj) {
      int dh = dh0 + jj;
      int phi = (dh & 7) ^ ((dh >> 3) & 7);
      VT[buf][dh][((((r >> 3) ^ phi) & 7) << 3) | (r & 7)] = vreg[jj];
    }
  };

  // softmax for one q-tile (s raw; P via exp2(fma)); writes P to Pl rows [plbase, plbase+16)
  auto softmax = [&](f32x4* s, float* mi, float* li, f32x4* acc, int q0w, int plbase, int j) {
    if (j * 64 + 63 > q0w) {  // mask needed (wave-uniform branch)
#pragma unroll
      for (int n = 0; n < 4; ++n)
#pragma unroll
        for (int r = 0; r < 4; ++r)
          if (j * 64 + n * 16 + lr > q0w + lk * 4 + r) s[n][r] = -__builtin_inff();
    }
    float tm[4];
#pragma unroll
    for (int r = 0; r < 4; ++r) {
      float x = fmaxf(fmaxf(s[0][r], s[1][r]), fmaxf(s[2][r], s[3][r]));
      x = fmaxf(x, __shfl_xor(x, 1));
      x = fmaxf(x, __shfl_xor(x, 2));
      x = fmaxf(x, __shfl_xor(x, 4));
      x = fmaxf(x, __shfl_xor(x, 8));
      tm[r] = x;
    }
    bool need = false;
#pragma unroll
    for (int r = 0; r < 4; ++r) need |= (tm[r] > mi[r] + 64.0f);  // defer-max, raw units
    if (__any(need)) {
#pragma unroll
      for (int r = 0; r < 4; ++r) {
        float mnew = fmaxf(mi[r], tm[r]);
        float alpha = __builtin_amdgcn_exp2f((mi[r] - mnew) * LG);
        mi[r] = mnew;
        li[r] *= alpha;
#pragma unroll
        for (int n = 0; n < 4; ++n) acc[n][r] *= alpha;
      }
    }
#pragma unroll
    for (int r = 0; r < 4; ++r) {
      float mc = -mi[r] * LG;
      float ps = 0.f;
#pragma unroll
      for (int n = 0; n < 4; ++n) {
        float pv = __builtin_amdgcn_exp2f(fmaf(s[n][r], LG, mc));
        ps += pv;
        Pl[w][plbase + lk * 4 + r][n * 16 + lr] = f2bf(pv);
      }
      ps += __shfl_xor(ps, 1);
      ps += __shfl_xor(ps, 2);
      ps += __shfl_xor(ps, 4);
      ps += __shfl_xor(ps, 8);
      li[r] += ps;
    }
  };

  // prologue: tile 0 into buffer 0
  stageK(0, 0);
  loadV(0);
  writeV(0);
  __syncthreads();

  for (int j = 0; j < ntB; ++j) {
    const int cur = j & 1;
    const bool more = (j + 1 < ntB);
    if (more) { stageK(j + 1, cur ^ 1); loadV(j + 1); }
    const bool doA = (j < ntA);

    // ---- QK^T for both q-tiles, kf shared ----
    f32x4 sA[4] = {}, sB[4] = {};
#pragma unroll
    for (int c = 0; c < 2; ++c)
#pragma unroll
      for (int n = 0; n < 4; ++n) {
        int row = n * 16 + lr;
        bf16x8 kf = *(const bf16x8*)((const char*)&Ks[cur][0][0] + row * 128 +
                                     ((((c * 4 + lk) ^ (row & 7)) & 7) << 4));
        sB[n] = __builtin_amdgcn_mfma_f32_16x16x32_bf16(qfB[c], kf, sB[n], 0, 0, 0);
        if (doA) sA[n] = __builtin_amdgcn_mfma_f32_16x16x32_bf16(qfA[c], kf, sA[n], 0, 0, 0);
      }

    softmax(sB, miB, liB, accB, q0B, 16, j);
    if (doA) softmax(sA, miA, liA, accA, q0A, 0, j);

    // ---- O += P @ V (vf shared between A and B) ----
#pragma unroll
    for (int c = 0; c < 2; ++c) {
      bf16x8 paB = *(const bf16x8*)&Pl[w][16 + lr][c * 32 + lk * 8];
      bf16x8 paA = {};
      if (doA) paA = *(const bf16x8*)&Pl[w][lr][c * 32 + lk * 8];
#pragma unroll
      for (int n = 0; n < 4; ++n) {
        int dh = n * 16 + lr;
        int phi = (dh & 7) ^ ((dh >> 3) & 7);
        bf16x8 vf = *(const bf16x8*)((const char*)&VT[cur][0][0] + dh * 128 +
                                     ((((c * 4 + lk) ^ phi) & 7) << 4));
        accB[n] = __builtin_amdgcn_mfma_f32_16x16x32_bf16(paB, vf, accB[n], 0, 0, 0);
        if (doA) accA[n] = __builtin_amdgcn_mfma_f32_16x16x32_bf16(paA, vf, accA[n], 0, 0, 0);
      }
    }

    if (more) writeV(cur ^ 1);
    __syncthreads();
  }

  // ---- epilogue: O = acc / l ----
#pragma unroll
  for (int r = 0; r < 4; ++r) {
    float invB = 1.0f / liB[r];
    size_t orowB = (rowQB + lk * 4 + r) * 1024 + h * 64;
#pragma unroll
    for (int n = 0; n < 4; ++n) O[orowB + n * 16 + lr] = f2bf(accB[n][r] * invB);
    float invA = 1.0f / liA[r];
    size_t orowA = (rowQA + lk * 4 + r) * 1024 + h * 64;
#pragma unroll
    for (int n = 0; n < 4; ++n) O[orowA + n * 16 + lr] = f2bf(accA[n][r] * invA);
  }
}

// ---------- launch ----------
extern "C" void kernel_launch(void* const* d_in, const int* in_sizes, int n_in,
                              void* d_out, int out_size, void* d_ws, size_t ws_size,
                              hipStream_t stream) {
  const float* x = (const float*)d_in[0];
  const float* w_qkv = (const float*)d_in[1];
  const float* b_qkv = (const float*)d_in[2];
  const float* w_out = (const float*)d_in[3];
  const float* b_out = (const float*)d_in[4];
  // d_in[5] = mask: always causal tril, handled analytically.

  char* ws = (char*)d_ws;
  u16* X16 = (u16*)(ws);                  // 16 MB; reused as O16 after GEMM1
  u16* WqkvT = (u16*)(ws + 16777216);     // 6 MB
  u16* WoutT = (u16*)(ws + 23068672);     // 2 MB
  u16* QKVb = (u16*)(ws + 25165824);      // 48 MB
  u16* O16 = X16;

  k_f32_to_bf16<<<8192, 256, 0, stream>>>(x, X16, 8388608 / 4);
  k_transpose_bf16<<<dim3(96, 32), 256, 0, stream>>>(w_qkv, WqkvT, 1024, 3072);
  k_transpose_bf16<<<dim3(32, 32), 256, 0, stream>>>(w_out, WoutT, 1024, 1024);
  k_gemm_bt<1><<<dim3(64, 24), 256, 0, stream>>>(X16, WqkvT, b_qkv, QKVb, 8192, 3072, 1024);
  k_attn<<<dim3(8, 64), 512, 0, stream>>>(QKVb, O16);
  k_gemm_bt<0><<<dim3(64, 8), 256, 0, stream>>>(O16, WoutT, b_out, d_out, 8192, 1024, 1024);
}

// Round 4
// 462.559 us; speedup vs baseline: 1.1904x; 1.1904x over previous
//
#include <hip/hip_runtime.h>
#include <hip/hip_bf16.h>

typedef unsigned short u16;
typedef __bf16 bf16x8 __attribute__((ext_vector_type(8)));
typedef float f32x4 __attribute__((ext_vector_type(4)));
typedef unsigned short u16x8 __attribute__((ext_vector_type(8)));

// ---------- helpers ----------
__device__ __forceinline__ void async_copy16(void* lds, const void* g) {
  __builtin_amdgcn_global_load_lds(
      (const __attribute__((address_space(1))) unsigned int*)g,
      (__attribute__((address_space(3))) unsigned int*)lds, 16, 0, 0);
}

__device__ __forceinline__ u16 f2bf(float f) {
  __hip_bfloat16 h = __float2bfloat16(f);
  u16 u;
  __builtin_memcpy(&u, &h, 2);
  return u;
}

// ---------- f32 -> bf16 convert (vectorized) ----------
__global__ void k_f32_to_bf16(const float* __restrict__ in, u16* __restrict__ out, int n4) {
  int i = blockIdx.x * blockDim.x + threadIdx.x;
  if (i >= n4) return;
  float4 v = ((const float4*)in)[i];
  ushort4 o;
  o.x = f2bf(v.x); o.y = f2bf(v.y); o.z = f2bf(v.z); o.w = f2bf(v.w);
  ((ushort4*)out)[i] = o;
}

// ---------- transpose RxC f32 -> CxR bf16 ----------
__global__ void k_transpose_bf16(const float* __restrict__ in, u16* __restrict__ out, int R, int C) {
  __shared__ float tile[32][33];
  int bx = blockIdx.x * 32;
  int by = blockIdx.y * 32;
  int tx = threadIdx.x & 31, ty = threadIdx.x >> 5;
  for (int i = ty; i < 32; i += 8) tile[i][tx] = in[(size_t)(by + i) * C + bx + tx];
  __syncthreads();
  for (int i = ty; i < 32; i += 8) out[(size_t)(bx + i) * R + by + tx] = f2bf(tile[tx][i]);
}

// ---------- GEMM: C(MxN) = A(MxK,bf16) @ Bt(NxK,bf16)^T + bias ----------
template <int OUT_BF16>
__global__ __launch_bounds__(256, 2) void k_gemm_bt(
    const u16* __restrict__ A, const u16* __restrict__ Bt,
    const float* __restrict__ bias, void* __restrict__ Cout,
    int M, int N, int K) {
  __shared__ __align__(16) u16 As[128][32];
  __shared__ __align__(16) u16 Bs[128][32];
  const int t = threadIdx.x;
  const int l = t & 63, w = t >> 6;
  const int lr = l & 15, lk = l >> 4;
  const int wr = w >> 1, wc = w & 1;
  const int m0 = blockIdx.x * 128, n0 = blockIdx.y * 128;

  f32x4 acc[4][4] = {};

  for (int k0 = 0; k0 < K; k0 += 32) {
    __syncthreads();
    for (int c = 0; c < 2; ++c) {
      int idx = c * 256 + t;
      int row = idx >> 2, slot = idx & 3;
      int sw = (slot ^ ((row >> 1) & 3)) << 3;
      async_copy16((char*)&As[0][0] + idx * 16, A + (size_t)(m0 + row) * K + k0 + sw);
      async_copy16((char*)&Bs[0][0] + idx * 16, Bt + (size_t)(n0 + row) * K + k0 + sw);
    }
    __syncthreads();
    bf16x8 af[4], bfr[4];
    for (int m = 0; m < 4; ++m) {
      int row = wr * 64 + m * 16 + lr;
      af[m] = *(const bf16x8*)((const char*)&As[0][0] + row * 64 + ((lk ^ ((row >> 1) & 3)) << 4));
    }
    for (int n = 0; n < 4; ++n) {
      int row = wc * 64 + n * 16 + lr;
      bfr[n] = *(const bf16x8*)((const char*)&Bs[0][0] + row * 64 + ((lk ^ ((row >> 1) & 3)) << 4));
    }
    for (int m = 0; m < 4; ++m)
      for (int n = 0; n < 4; ++n)
        acc[m][n] = __builtin_amdgcn_mfma_f32_16x16x32_bf16(af[m], bfr[n], acc[m][n], 0, 0, 0);
  }

  for (int n = 0; n < 4; ++n) {
    int col = n0 + wc * 64 + n * 16 + lr;
    float bv = bias[col];
    for (int m = 0; m < 4; ++m) {
      int rowb = m0 + wr * 64 + m * 16 + lk * 4;
      for (int r = 0; r < 4; ++r) {
        float v = acc[m][n][r] + bv;
        size_t off = (size_t)(rowb + r) * N + col;
        if constexpr (OUT_BF16) ((u16*)Cout)[off] = f2bf(v);
        else ((float*)Cout)[off] = v;
      }
    }
  }
}

// ---------- flash attention, causal, bf16 ----------
// grid (B*H, 16); block 256 = 4 waves x 16 q-rows per q-tile. Block (bh, p)
// handles 64-row q-tiles p (A) and 31-p (B) -> 33 uniform KV-tile-units.
// LDS = 40960 B exactly -> 4 blocks/CU; VGPR capped 128 -> 16 waves/CU.
// KV double-buffered, 1 barrier/tile; Pl reused B-then-A (same-wave lgkm order).
__global__ __launch_bounds__(256, 4) void k_attn(
    const u16* __restrict__ QKV,  // (B*S) x 3072 bf16: [Q|K|V]
    u16* __restrict__ O) {        // (B*S) x 1024 bf16
  const int bh = blockIdx.x;  // 0..63 (fastest -> same-bh blocks share an XCD)
  const int p = blockIdx.y;   // 0..15
  const int b = bh >> 4, h = bh & 15;
  const int t = threadIdx.x;
  const int l = t & 63, w = t >> 6;  // 4 waves
  const int lr = l & 15, lk = l >> 4;
  constexpr float LG = 0.18033688f;  // 0.125 * log2(e)

  __shared__ __align__(16) u16 Ks[2][64][64];  // key tiles (src-swizzled), dbuf: 16 KB
  __shared__ __align__(16) u16 VT[2][64][64];  // V^T tiles (two-sided swizzle), dbuf: 16 KB
  __shared__ __align__(16) u16 Pl[4][16][64];  // per-wave P, XOR-swizzled (chunk^=row&7): 8 KB

  const int qtA = p, qtB = 31 - p;
  const int ntA = qtA + 1, ntB = qtB + 1;  // sum = 33
  const int q0A = qtA * 64 + w * 16, q0B = qtB * 64 + w * 16;
  const size_t rowQA = (size_t)b * 2048 + q0A;
  const size_t rowQB = (size_t)b * 2048 + q0B;

  bf16x8 qfA[2], qfB[2];
#pragma unroll
  for (int c = 0; c < 2; ++c) {
    qfA[c] = *(const bf16x8*)(QKV + (rowQA + lr) * 3072 + h * 64 + c * 32 + lk * 8);
    qfB[c] = *(const bf16x8*)(QKV + (rowQB + lr) * 3072 + h * 64 + c * 32 + lk * 8);
  }

  f32x4 accA[4] = {}, accB[4] = {};
  float miA[4], liA[4], miB[4], liB[4];
#pragma unroll
  for (int r = 0; r < 4; ++r) {
    miA[r] = -__builtin_inff(); liA[r] = 0.f;
    miB[r] = -__builtin_inff(); liB[r] = 0.f;
  }

  const u16* Kb0 = QKV + (size_t)b * 2048 * 3072 + 1024 + h * 64;
  const u16* Vb0 = Kb0 + 1024;
  u16x8 vreg[2];

  auto stageK = [&](int j, int buf) {
#pragma unroll
    for (int c = 0; c < 2; ++c) {
      int gi = c * 256 + t;
      int row = gi >> 3, slot = gi & 7;
      async_copy16((char*)&Ks[buf][0][0] + gi * 16,
                   Kb0 + ((size_t)j * 64 + row) * 3072 + ((slot ^ (row & 7)) << 3));
    }
  };
  auto loadV = [&](int j) {
#pragma unroll
    for (int c = 0; c < 2; ++c) {
      int r = c * 32 + (t >> 3), dh0 = (t & 7) << 3;
      vreg[c] = *(const u16x8*)(Vb0 + ((size_t)j * 64 + r) * 3072 + dh0);
    }
  };
  auto writeV = [&](int buf) {
#pragma unroll
    for (int c = 0; c < 2; ++c) {
      int r = c * 32 + (t >> 3), dh0 = (t & 7) << 3;
#pragma unroll
      for (int jj = 0; jj < 8; ++jj) {
        int dh = dh0 + jj;
        int phi = (dh & 7) ^ ((dh >> 3) & 7);
        VT[buf][dh][((((r >> 3) ^ phi) & 7) << 3) | (r & 7)] = vreg[c][jj];
      }
    }
  };

  // softmax for one 16-row q-tile; writes P (bf16) into Pl[w] swizzled
  auto softmax = [&](f32x4 (&s)[4], float (&mi)[4], float (&li)[4], f32x4 (&acc)[4],
                     int q0w, int j) {
    if (j * 64 + 63 > q0w) {  // wave-uniform mask skip
#pragma unroll
      for (int n = 0; n < 4; ++n)
#pragma unroll
        for (int r = 0; r < 4; ++r)
          if (j * 64 + n * 16 + lr > q0w + lk * 4 + r) s[n][r] = -__builtin_inff();
    }
    float tm[4];
#pragma unroll
    for (int r = 0; r < 4; ++r) {
      float x = fmaxf(fmaxf(s[0][r], s[1][r]), fmaxf(s[2][r], s[3][r]));
      x = fmaxf(x, __shfl_xor(x, 1));
      x = fmaxf(x, __shfl_xor(x, 2));
      x = fmaxf(x, __shfl_xor(x, 4));
      x = fmaxf(x, __shfl_xor(x, 8));
      tm[r] = x;
    }
    bool need = false;
#pragma unroll
    for (int r = 0; r < 4; ++r) need |= (tm[r] > mi[r] + 64.0f);  // defer-max, raw units
    if (__any(need)) {
#pragma unroll
      for (int r = 0; r < 4; ++r) {
        float mnew = fmaxf(mi[r], tm[r]);
        float alpha = __builtin_amdgcn_exp2f((mi[r] - mnew) * LG);
        mi[r] = mnew;
        li[r] *= alpha;
#pragma unroll
        for (int n = 0; n < 4; ++n) acc[n][r] *= alpha;
      }
    }
    u16* pw = &Pl[w][0][0];
#pragma unroll
    for (int r = 0; r < 4; ++r) {
      int row = lk * 4 + r;
      float mc = -mi[r] * LG;
      float ps = 0.f;
#pragma unroll
      for (int n = 0; n < 4; ++n) {
        float pv = __builtin_amdgcn_exp2f(fmaf(s[n][r], LG, mc));
        ps += pv;
        pw[row * 64 + (((n * 2 + (lr >> 3)) ^ (row & 7)) << 3) + (lr & 7)] = f2bf(pv);
      }
      ps += __shfl_xor(ps, 1);
      ps += __shfl_xor(ps, 2);
      ps += __shfl_xor(ps, 4);
      ps += __shfl_xor(ps, 8);
      li[r] += ps;
    }
  };

  // PV: O += P @ V for the tile currently in Pl[w]
  auto pv = [&](f32x4 (&acc)[4], int cur) {
    const u16* pw = &Pl[w][0][0];
#pragma unroll
    for (int c = 0; c < 2; ++c) {
      bf16x8 pa = *(const bf16x8*)(pw + lr * 64 + (((c * 4 + lk) ^ (lr & 7)) << 3));
#pragma unroll
      for (int n = 0; n < 4; ++n) {
        int dh = n * 16 + lr;
        int phi = (dh & 7) ^ ((dh >> 3) & 7);
        bf16x8 vf = *(const bf16x8*)((const char*)&VT[cur][0][0] + dh * 128 +
                                     ((((c * 4 + lk) ^ phi) & 7) << 4));
        acc[n] = __builtin_amdgcn_mfma_f32_16x16x32_bf16(pa, vf, acc[n], 0, 0, 0);
      }
    }
  };

  // prologue: tile 0 into buffer 0
  stageK(0, 0);
  loadV(0);
  writeV(0);
  __syncthreads();

  for (int j = 0; j < ntB; ++j) {
    const int cur = j & 1;
    const bool more = (j + 1 < ntB);
    if (more) { stageK(j + 1, cur ^ 1); loadV(j + 1); }
    const bool doA = (j < ntA);

    // ---- QK^T for both q-tiles, kf shared ----
    f32x4 sA[4] = {}, sB[4] = {};
#pragma unroll
    for (int c = 0; c < 2; ++c)
#pragma unroll
      for (int n = 0; n < 4; ++n) {
        int row = n * 16 + lr;
        bf16x8 kf = *(const bf16x8*)((const char*)&Ks[cur][0][0] + row * 128 +
                                     ((((c * 4 + lk) ^ (row & 7)) & 7) << 4));
        sB[n] = __builtin_amdgcn_mfma_f32_16x16x32_bf16(qfB[c], kf, sB[n], 0, 0, 0);
        if (doA) sA[n] = __builtin_amdgcn_mfma_f32_16x16x32_bf16(qfA[c], kf, sA[n], 0, 0, 0);
      }

    // ---- B then A through the shared Pl buffer ----
    softmax(sB, miB, liB, accB, q0B, j);
    pv(accB, cur);
    if (doA) {
      softmax(sA, miA, liA, accA, q0A, j);  // WAR on Pl ordered by lgkmcnt (same wave)
      pv(accA, cur);
    }

    if (more) writeV(cur ^ 1);
    __syncthreads();
  }

  // ---- epilogue: O = acc / l ----
#pragma unroll
  for (int r = 0; r < 4; ++r) {
    float invB = 1.0f / liB[r];
    size_t orowB = (rowQB + lk * 4 + r) * 1024 + h * 64;
#pragma unroll
    for (int n = 0; n < 4; ++n) O[orowB + n * 16 + lr] = f2bf(accB[n][r] * invB);
    float invA = 1.0f / liA[r];
    size_t orowA = (rowQA + lk * 4 + r) * 1024 + h * 64;
#pragma unroll
    for (int n = 0; n < 4; ++n) O[orowA + n * 16 + lr] = f2bf(accA[n][r] * invA);
  }
}

// ---------- launch ----------
extern "C" void kernel_launch(void* const* d_in, const int* in_sizes, int n_in,
                              void* d_out, int out_size, void* d_ws, size_t ws_size,
                              hipStream_t stream) {
  const float* x = (const float*)d_in[0];
  const float* w_qkv = (const float*)d_in[1];
  const float* b_qkv = (const float*)d_in[2];
  const float* w_out = (const float*)d_in[3];
  const float* b_out = (const float*)d_in[4];
  // d_in[5] = mask: always causal tril, handled analytically.

  char* ws = (char*)d_ws;
  u16* X16 = (u16*)(ws);                  // 16 MB; reused as O16 after GEMM1
  u16* WqkvT = (u16*)(ws + 16777216);     // 6 MB
  u16* WoutT = (u16*)(ws + 23068672);     // 2 MB
  u16* QKVb = (u16*)(ws + 25165824);      // 48 MB
  u16* O16 = X16;

  k_f32_to_bf16<<<8192, 256, 0, stream>>>(x, X16, 8388608 / 4);
  k_transpose_bf16<<<dim3(96, 32), 256, 0, stream>>>(w_qkv, WqkvT, 1024, 3072);
  k_transpose_bf16<<<dim3(32, 32), 256, 0, stream>>>(w_out, WoutT, 1024, 1024);
  k_gemm_bt<1><<<dim3(64, 24), 256, 0, stream>>>(X16, WqkvT, b_qkv, QKVb, 8192, 3072, 1024);
  k_attn<<<dim3(64, 16), 256, 0, stream>>>(QKVb, O16);
  k_gemm_bt<0><<<dim3(64, 8), 256, 0, stream>>>(O16, WoutT, b_out, d_out, 8192, 1024, 1024);
}

// Round 5
// 245.308 us; speedup vs baseline: 2.2447x; 1.8856x over previous
//
#include <hip/hip_runtime.h>
#include <hip/hip_bf16.h>

typedef unsigned short u16;
typedef __bf16 bf16x8 __attribute__((ext_vector_type(8)));
typedef float f32x4 __attribute__((ext_vector_type(4)));
typedef unsigned short u16x8 __attribute__((ext_vector_type(8)));

// ---------- helpers ----------
__device__ __forceinline__ void async_copy16(void* lds, const void* g) {
  __builtin_amdgcn_global_load_lds(
      (const __attribute__((address_space(1))) unsigned int*)g,
      (__attribute__((address_space(3))) unsigned int*)lds, 16, 0, 0);
}

__device__ __forceinline__ u16 f2bf(float f) {
  __hip_bfloat16 h = __float2bfloat16(f);
  u16 u;
  __builtin_memcpy(&u, &h, 2);
  return u;
}

// ---------- f32 -> bf16 convert (vectorized) ----------
__global__ void k_f32_to_bf16(const float* __restrict__ in, u16* __restrict__ out, int n4) {
  int i = blockIdx.x * blockDim.x + threadIdx.x;
  if (i >= n4) return;
  float4 v = ((const float4*)in)[i];
  ushort4 o;
  o.x = f2bf(v.x); o.y = f2bf(v.y); o.z = f2bf(v.z); o.w = f2bf(v.w);
  ((ushort4*)out)[i] = o;
}

// ---------- transpose RxC f32 -> CxR bf16 ----------
__global__ void k_transpose_bf16(const float* __restrict__ in, u16* __restrict__ out, int R, int C) {
  __shared__ float tile[32][33];
  int bx = blockIdx.x * 32;
  int by = blockIdx.y * 32;
  int tx = threadIdx.x & 31, ty = threadIdx.x >> 5;
  for (int i = ty; i < 32; i += 8) tile[i][tx] = in[(size_t)(by + i) * C + bx + tx];
  __syncthreads();
  for (int i = ty; i < 32; i += 8) out[(size_t)(bx + i) * R + by + tx] = f2bf(tile[tx][i]);
}

// ---------- GEMM: C(MxN) = A(MxK,bf16) @ Bt(NxK,bf16)^T + bias ----------
template <int OUT_BF16>
__global__ __launch_bounds__(256, 2) void k_gemm_bt(
    const u16* __restrict__ A, const u16* __restrict__ Bt,
    const float* __restrict__ bias, void* __restrict__ Cout,
    int M, int N, int K) {
  __shared__ __align__(16) u16 As[128][32];
  __shared__ __align__(16) u16 Bs[128][32];
  const int t = threadIdx.x;
  const int l = t & 63, w = t >> 6;
  const int lr = l & 15, lk = l >> 4;
  const int wr = w >> 1, wc = w & 1;
  const int m0 = blockIdx.x * 128, n0 = blockIdx.y * 128;

  f32x4 acc[4][4] = {};

  for (int k0 = 0; k0 < K; k0 += 32) {
    __syncthreads();
    for (int c = 0; c < 2; ++c) {
      int idx = c * 256 + t;
      int row = idx >> 2, slot = idx & 3;
      int sw = (slot ^ ((row >> 1) & 3)) << 3;
      async_copy16((char*)&As[0][0] + idx * 16, A + (size_t)(m0 + row) * K + k0 + sw);
      async_copy16((char*)&Bs[0][0] + idx * 16, Bt + (size_t)(n0 + row) * K + k0 + sw);
    }
    __syncthreads();
    bf16x8 af[4], bfr[4];
    for (int m = 0; m < 4; ++m) {
      int row = wr * 64 + m * 16 + lr;
      af[m] = *(const bf16x8*)((const char*)&As[0][0] + row * 64 + ((lk ^ ((row >> 1) & 3)) << 4));
    }
    for (int n = 0; n < 4; ++n) {
      int row = wc * 64 + n * 16 + lr;
      bfr[n] = *(const bf16x8*)((const char*)&Bs[0][0] + row * 64 + ((lk ^ ((row >> 1) & 3)) << 4));
    }
    for (int m = 0; m < 4; ++m)
      for (int n = 0; n < 4; ++n)
        acc[m][n] = __builtin_amdgcn_mfma_f32_16x16x32_bf16(af[m], bfr[n], acc[m][n], 0, 0, 0);
  }

  for (int n = 0; n < 4; ++n) {
    int col = n0 + wc * 64 + n * 16 + lr;
    float bv = bias[col];
    for (int m = 0; m < 4; ++m) {
      int rowb = m0 + wr * 64 + m * 16 + lk * 4;
      for (int r = 0; r < 4; ++r) {
        float v = acc[m][n][r] + bv;
        size_t off = (size_t)(rowb + r) * N + col;
        if constexpr (OUT_BF16) ((u16*)Cout)[off] = f2bf(v);
        else ((float*)Cout)[off] = v;
      }
    }
  }
}

// ---------- flash attention, causal, bf16 ----------
// grid (B*H, 16); block 256 = 4 waves x 16 q-rows per q-tile. Block (bh, p)
// handles 64-row q-tiles p (A) and 31-p (B) -> 33 uniform KV-tile-units.
// LDS = 40960 B exactly -> 4 blocks/CU capacity; launch_bounds kept at
// min-waves=2 (R3/R4 lesson: min-waves=4 halves the unified reg budget and
// spills all softmax state to scratch -> 950 MB FETCH. Let VGPR settle ~128;
// HW still packs 4 blocks/CU when the binary fits).
__global__ __launch_bounds__(256, 2) void k_attn(
    const u16* __restrict__ QKV,  // (B*S) x 3072 bf16: [Q|K|V]
    u16* __restrict__ O) {        // (B*S) x 1024 bf16
  const int bh = blockIdx.x;  // 0..63 (fastest; bh%8 pins each bh-stream to one XCD)
  const int p = blockIdx.y;   // 0..15
  const int b = bh >> 4, h = bh & 15;
  const int t = threadIdx.x;
  const int l = t & 63, w = t >> 6;  // 4 waves
  const int lr = l & 15, lk = l >> 4;
  constexpr float LG = 0.18033688f;  // 0.125 * log2(e)

  __shared__ __align__(16) u16 Ks[2][64][64];  // key tiles (src-swizzled), dbuf: 16 KB
  __shared__ __align__(16) u16 VT[2][64][64];  // V^T tiles (two-sided swizzle), dbuf: 16 KB
  __shared__ __align__(16) u16 Pl[4][16][64];  // per-wave P, XOR-swizzled (chunk^=row&7): 8 KB

  const int qtA = p, qtB = 31 - p;
  const int ntA = qtA + 1, ntB = qtB + 1;  // sum = 33
  const int q0A = qtA * 64 + w * 16, q0B = qtB * 64 + w * 16;
  const size_t rowQA = (size_t)b * 2048 + q0A;
  const size_t rowQB = (size_t)b * 2048 + q0B;

  bf16x8 qfA[2], qfB[2];
#pragma unroll
  for (int c = 0; c < 2; ++c) {
    qfA[c] = *(const bf16x8*)(QKV + (rowQA + lr) * 3072 + h * 64 + c * 32 + lk * 8);
    qfB[c] = *(const bf16x8*)(QKV + (rowQB + lr) * 3072 + h * 64 + c * 32 + lk * 8);
  }

  f32x4 accA[4] = {}, accB[4] = {};
  float miA[4], liA[4], miB[4], liB[4];
#pragma unroll
  for (int r = 0; r < 4; ++r) {
    miA[r] = -__builtin_inff(); liA[r] = 0.f;
    miB[r] = -__builtin_inff(); liB[r] = 0.f;
  }

  const u16* Kb0 = QKV + (size_t)b * 2048 * 3072 + 1024 + h * 64;
  const u16* Vb0 = Kb0 + 1024;
  u16x8 vreg[2];

  auto stageK = [&](int j, int buf) {
#pragma unroll
    for (int c = 0; c < 2; ++c) {
      int gi = c * 256 + t;
      int row = gi >> 3, slot = gi & 7;
      async_copy16((char*)&Ks[buf][0][0] + gi * 16,
                   Kb0 + ((size_t)j * 64 + row) * 3072 + ((slot ^ (row & 7)) << 3));
    }
  };
  auto loadV = [&](int j) {
#pragma unroll
    for (int c = 0; c < 2; ++c) {
      int r = c * 32 + (t >> 3), dh0 = (t & 7) << 3;
      vreg[c] = *(const u16x8*)(Vb0 + ((size_t)j * 64 + r) * 3072 + dh0);
    }
  };
  auto writeV = [&](int buf) {
#pragma unroll
    for (int c = 0; c < 2; ++c) {
      int r = c * 32 + (t >> 3), dh0 = (t & 7) << 3;
#pragma unroll
      for (int jj = 0; jj < 8; ++jj) {
        int dh = dh0 + jj;
        int phi = (dh & 7) ^ ((dh >> 3) & 7);
        VT[buf][dh][((((r >> 3) ^ phi) & 7) << 3) | (r & 7)] = vreg[c][jj];
      }
    }
  };

  // softmax for one 16-row q-tile; writes P (bf16) into Pl[w] swizzled
  auto softmax = [&](f32x4 (&s)[4], float (&mi)[4], float (&li)[4], f32x4 (&acc)[4],
                     int q0w, int j) {
    if (j * 64 + 63 > q0w) {  // wave-uniform mask skip
#pragma unroll
      for (int n = 0; n < 4; ++n)
#pragma unroll
        for (int r = 0; r < 4; ++r)
          if (j * 64 + n * 16 + lr > q0w + lk * 4 + r) s[n][r] = -__builtin_inff();
    }
    float tm[4];
#pragma unroll
    for (int r = 0; r < 4; ++r) {
      float x = fmaxf(fmaxf(s[0][r], s[1][r]), fmaxf(s[2][r], s[3][r]));
      x = fmaxf(x, __shfl_xor(x, 1));
      x = fmaxf(x, __shfl_xor(x, 2));
      x = fmaxf(x, __shfl_xor(x, 4));
      x = fmaxf(x, __shfl_xor(x, 8));
      tm[r] = x;
    }
    bool need = false;
#pragma unroll
    for (int r = 0; r < 4; ++r) need |= (tm[r] > mi[r] + 64.0f);  // defer-max, raw units
    if (__any(need)) {
#pragma unroll
      for (int r = 0; r < 4; ++r) {
        float mnew = fmaxf(mi[r], tm[r]);
        float alpha = __builtin_amdgcn_exp2f((mi[r] - mnew) * LG);
        mi[r] = mnew;
        li[r] *= alpha;
#pragma unroll
        for (int n = 0; n < 4; ++n) acc[n][r] *= alpha;
      }
    }
    u16* pw = &Pl[w][0][0];
#pragma unroll
    for (int r = 0; r < 4; ++r) {
      int row = lk * 4 + r;
      float mc = -mi[r] * LG;
      float ps = 0.f;
#pragma unroll
      for (int n = 0; n < 4; ++n) {
        float pv = __builtin_amdgcn_exp2f(fmaf(s[n][r], LG, mc));
        ps += pv;
        pw[row * 64 + (((n * 2 + (lr >> 3)) ^ (row & 7)) << 3) + (lr & 7)] = f2bf(pv);
      }
      ps += __shfl_xor(ps, 1);
      ps += __shfl_xor(ps, 2);
      ps += __shfl_xor(ps, 4);
      ps += __shfl_xor(ps, 8);
      li[r] += ps;
    }
  };

  // PV: O += P @ V for the tile currently in Pl[w]
  auto pv = [&](f32x4 (&acc)[4], int cur) {
    const u16* pw = &Pl[w][0][0];
#pragma unroll
    for (int c = 0; c < 2; ++c) {
      bf16x8 pa = *(const bf16x8*)(pw + lr * 64 + (((c * 4 + lk) ^ (lr & 7)) << 3));
#pragma unroll
      for (int n = 0; n < 4; ++n) {
        int dh = n * 16 + lr;
        int phi = (dh & 7) ^ ((dh >> 3) & 7);
        bf16x8 vf = *(const bf16x8*)((const char*)&VT[cur][0][0] + dh * 128 +
                                     ((((c * 4 + lk) ^ phi) & 7) << 4));
        acc[n] = __builtin_amdgcn_mfma_f32_16x16x32_bf16(pa, vf, acc[n], 0, 0, 0);
      }
    }
  };

  // prologue: tile 0 into buffer 0
  stageK(0, 0);
  loadV(0);
  writeV(0);
  __syncthreads();

  for (int j = 0; j < ntB; ++j) {
    const int cur = j & 1;
    const bool more = (j + 1 < ntB);
    if (more) { stageK(j + 1, cur ^ 1); loadV(j + 1); }
    const bool doA = (j < ntA);

    // ---- QK^T for both q-tiles, kf shared ----
    f32x4 sA[4] = {}, sB[4] = {};
#pragma unroll
    for (int c = 0; c < 2; ++c)
#pragma unroll
      for (int n = 0; n < 4; ++n) {
        int row = n * 16 + lr;
        bf16x8 kf = *(const bf16x8*)((const char*)&Ks[cur][0][0] + row * 128 +
                                     ((((c * 4 + lk) ^ (row & 7)) & 7) << 4));
        sB[n] = __builtin_amdgcn_mfma_f32_16x16x32_bf16(qfB[c], kf, sB[n], 0, 0, 0);
        if (doA) sA[n] = __builtin_amdgcn_mfma_f32_16x16x32_bf16(qfA[c], kf, sA[n], 0, 0, 0);
      }

    // ---- B then A through the shared Pl buffer ----
    softmax(sB, miB, liB, accB, q0B, j);
    pv(accB, cur);
    if (doA) {
      softmax(sA, miA, liA, accA, q0A, j);  // WAR on Pl ordered by lgkmcnt (same wave)
      pv(accA, cur);
    }

    if (more) writeV(cur ^ 1);
    __syncthreads();
  }

  // ---- epilogue: O = acc / l ----
#pragma unroll
  for (int r = 0; r < 4; ++r) {
    float invB = 1.0f / liB[r];
    size_t orowB = (rowQB + lk * 4 + r) * 1024 + h * 64;
#pragma unroll
    for (int n = 0; n < 4; ++n) O[orowB + n * 16 + lr] = f2bf(accB[n][r] * invB);
    float invA = 1.0f / liA[r];
    size_t orowA = (rowQA + lk * 4 + r) * 1024 + h * 64;
#pragma unroll
    for (int n = 0; n < 4; ++n) O[orowA + n * 16 + lr] = f2bf(accA[n][r] * invA);
  }
}

// ---------- launch ----------
extern "C" void kernel_launch(void* const* d_in, const int* in_sizes, int n_in,
                              void* d_out, int out_size, void* d_ws, size_t ws_size,
                              hipStream_t stream) {
  const float* x = (const float*)d_in[0];
  const float* w_qkv = (const float*)d_in[1];
  const float* b_qkv = (const float*)d_in[2];
  const float* w_out = (const float*)d_in[3];
  const float* b_out = (const float*)d_in[4];
  // d_in[5] = mask: always causal tril, handled analytically.

  char* ws = (char*)d_ws;
  u16* X16 = (u16*)(ws);                  // 16 MB; reused as O16 after GEMM1
  u16* WqkvT = (u16*)(ws + 16777216);     // 6 MB
  u16* WoutT = (u16*)(ws + 23068672);     // 2 MB
  u16* QKVb = (u16*)(ws + 25165824);      // 48 MB
  u16* O16 = X16;

  k_f32_to_bf16<<<8192, 256, 0, stream>>>(x, X16, 8388608 / 4);
  k_transpose_bf16<<<dim3(96, 32), 256, 0, stream>>>(w_qkv, WqkvT, 1024, 3072);
  k_transpose_bf16<<<dim3(32, 32), 256, 0, stream>>>(w_out, WoutT, 1024, 1024);
  k_gemm_bt<1><<<dim3(64, 24), 256, 0, stream>>>(X16, WqkvT, b_qkv, QKVb, 8192, 3072, 1024);
  k_attn<<<dim3(64, 16), 256, 0, stream>>>(QKVb, O16);
  k_gemm_bt<0><<<dim3(64, 8), 256, 0, stream>>>(O16, WoutT, b_out, d_out, 8192, 1024, 1024);
}